// Round 6
// baseline (295.248 us; speedup 1.0000x reference)
//
#include <hip/hip_runtime.h>

#define NB   2
#define NHD  8
#define BH   16
#define HD   16
#define N0   9216
#define N1   2304
#define N2   576
#define W0_  96
#define W1_  48
#define W2_  24
#define M_TOT 18432
#define TEMP 0.25f

// ---------------- projection GEMM: dst[(b,h,n,d)] = sum_c A[m][c] * W[o][c] ----------------
__global__ __launch_bounds__(256) void k_proj(const float* __restrict__ x, const float* __restrict__ tg,
    const float* __restrict__ Wq, const float* __restrict__ Wk, const float* __restrict__ Wv,
    float* __restrict__ q0, float* __restrict__ k0, float* __restrict__ v0)
{
    __shared__ __align__(16) float At[16][68];   // [k][row]
    __shared__ __align__(16) float Wt[16][132];  // [k][o]
    const int t = threadIdx.x;
    const int which = blockIdx.y;
    const float* A  = (which==0)? x : tg;
    const float* Wm = (which==0)? Wq : (which==1? Wk : Wv);
    float* dst      = (which==0)? q0 : (which==1? k0 : v0);
    const int m0 = blockIdx.x * 64;
    const int tx = t & 15, ty = t >> 4;

    float acc[4][8];
#pragma unroll
    for(int i=0;i<4;i++)
#pragma unroll
        for(int j=0;j<8;j++) acc[i][j]=0.f;

    const int ar = t>>2, akq = (t&3)*4;
    const int wo = t>>1, wkq = (t&1)*8;

    for(int kc=0;kc<128;kc+=16){
        float4 av = *(const float4*)(A + (size_t)(m0+ar)*128 + kc + akq);
        At[akq+0][ar] = av.x;
        At[akq+1][ar] = av.y;
        At[akq+2][ar] = av.z;
        At[akq+3][ar] = av.w;
        float4 w0 = *(const float4*)(Wm + (size_t)wo*128 + kc + wkq);
        float4 w1 = *(const float4*)(Wm + (size_t)wo*128 + kc + wkq + 4);
        Wt[wkq+0][wo] = w0.x; Wt[wkq+1][wo] = w0.y;
        Wt[wkq+2][wo] = w0.z; Wt[wkq+3][wo] = w0.w;
        Wt[wkq+4][wo] = w1.x; Wt[wkq+5][wo] = w1.y;
        Wt[wkq+6][wo] = w1.z; Wt[wkq+7][wo] = w1.w;
        __syncthreads();
#pragma unroll
        for(int kk=0;kk<16;kk++){
            float4 a4 = *(const float4*)&At[kk][ty*4];
            float4 wa = *(const float4*)&Wt[kk][tx*4];
            float4 wb = *(const float4*)&Wt[kk][64 + tx*4];
            float avr[4] = {a4.x,a4.y,a4.z,a4.w};
            float wvr[8] = {wa.x,wa.y,wa.z,wa.w, wb.x,wb.y,wb.z,wb.w};
#pragma unroll
            for(int i=0;i<4;i++)
#pragma unroll
                for(int j=0;j<8;j++) acc[i][j] += avr[i]*wvr[j];
        }
        __syncthreads();
    }
#pragma unroll
    for(int i=0;i<4;i++){
        int m = m0 + ty*4 + i;
        int b = m / N0; int n = m - b*N0;
#pragma unroll
        for(int j=0;j<8;j++){
            int o = (j<4)? (tx*4+j) : (64 + tx*4 + (j-4));
            int h = o>>4, d = o&15;
            dst[((size_t)(b*NHD+h)*N0 + n)*16 + d] = acc[i][j];
        }
    }
}

// ---------------- 2x2 average pooling, treats q/k/v contiguously as [48][Nin][16] ----------------
__global__ __launch_bounds__(256) void k_pool(const float4* __restrict__ src, float4* __restrict__ dst,
                                              int Win, int Nin, int Nout, int total)
{
    int tid = blockIdx.x*256 + threadIdx.x;
    if (tid >= total) return;
    int d4 = tid & 3;
    int rest = tid >> 2;
    int n = rest % Nout; int g = rest / Nout;
    int Wout = Win>>1;
    int yo = n / Wout, xo = n - yo*Wout;
    int cbase = (2*yo)*Win + 2*xo;
    const float4* s = src + (size_t)g*Nin*4;
    float4 a = s[(cbase      )*4 + d4];
    float4 b = s[(cbase+1    )*4 + d4];
    float4 c = s[(cbase+Win  )*4 + d4];
    float4 d = s[(cbase+Win+1)*4 + d4];
    float4 o;
    o.x = 0.25f*(a.x+b.x+c.x+d.x);
    o.y = 0.25f*(a.y+b.y+c.y+d.y);
    o.z = 0.25f*(a.z+b.z+c.z+d.z);
    o.w = 0.25f*(a.w+b.w+c.w+d.w);
    dst[((size_t)g*Nout + n)*4 + d4] = o;
}

// ---- level-2 full attention + top-16: LDS-free, 2 queries/wave, R4-bit-identical numerics ----
__global__ __launch_bounds__(256) void k_attn2(const float* __restrict__ q2, const float* __restrict__ k2,
    const float* __restrict__ v2, float* __restrict__ msg2, int* __restrict__ idx2)
{
    const int bh = blockIdx.x;
    const int wv = threadIdx.x>>6, lane = threadIdx.x&63;
    const int qbase = blockIdx.y*8 + wv*2;   // queries qbase, qbase+1

    const float4* qp = (const float4*)(q2 + ((size_t)bh*N2 + qbase)*16);
    float qa[16], qb[16];
#pragma unroll
    for(int dq=0;dq<4;dq++){
        float4 va = qp[dq];
        qa[dq*4+0]=va.x; qa[dq*4+1]=va.y; qa[dq*4+2]=va.z; qa[dq*4+3]=va.w;
        float4 vb = qp[4+dq];
        qb[dq*4+0]=vb.x; qb[dq*4+1]=vb.y; qb[dq*4+2]=vb.z; qb[dq*4+3]=vb.w;
    }

    const float4* kg = (const float4*)(k2 + (size_t)bh*N2*16);
    const float4* vg = (const float4*)(v2 + (size_t)bh*N2*16);

    // pass 1: scores + running max (matches R4 order: dot, *TEMP, fmax chain, then butterfly)
    float eva[9], evb[9];
    float mxa = -1e30f, mxb = -1e30f;
#pragma unroll
    for(int t9=0;t9<9;t9++){
        int m = t9*64 + lane;
        float kr[16];
#pragma unroll
        for(int dq=0;dq<4;dq++){
            float4 kv = kg[m*4+dq];
            kr[dq*4+0]=kv.x; kr[dq*4+1]=kv.y; kr[dq*4+2]=kv.z; kr[dq*4+3]=kv.w;
        }
        float sa=0.f, sb=0.f;
#pragma unroll
        for(int d=0;d<16;d++){ sa += qa[d]*kr[d]; sb += qb[d]*kr[d]; }
        sa *= TEMP; sb *= TEMP;
        eva[t9]=sa; evb[t9]=sb;
        mxa = fmaxf(mxa, sa); mxb = fmaxf(mxb, sb);
    }
#pragma unroll
    for(int st=1; st<64; st<<=1){
        mxa = fmaxf(mxa, __shfl_xor(mxa, st));
        mxb = fmaxf(mxb, __shfl_xor(mxb, st));
    }

    // pass 2: exp(s-mx), sum, and P·V accumulation (v rows from L2)
    float suma=0.f, sumb=0.f;
    float acca[16], accb[16];
#pragma unroll
    for(int d=0;d<16;d++){ acca[d]=0.f; accb[d]=0.f; }
#pragma unroll
    for(int t9=0;t9<9;t9++){
        int m = t9*64 + lane;
        float ea = expf(eva[t9]-mxa);
        float eb = expf(evb[t9]-mxb);
        eva[t9]=ea; evb[t9]=eb;
        suma += ea; sumb += eb;
        float vr[16];
#pragma unroll
        for(int dq=0;dq<4;dq++){
            float4 vv = vg[m*4+dq];
            vr[dq*4+0]=vv.x; vr[dq*4+1]=vv.y; vr[dq*4+2]=vv.z; vr[dq*4+3]=vv.w;
        }
#pragma unroll
        for(int d=0;d<16;d++){ acca[d] += ea*vr[d]; accb[d] += eb*vr[d]; }
    }
#pragma unroll
    for(int st=1; st<64; st<<=1){
        suma += __shfl_xor(suma, st);
        sumb += __shfl_xor(sumb, st);
    }

    // dim-splitting butterfly reductions (independent chains for a and b)
    const bool b5 = (lane & 32) != 0;
    float r8a[8], r8b[8];
#pragma unroll
    for(int i=0;i<8;i++){
        float sna  = b5 ? acca[i]   : acca[i+8];
        float kpa  = b5 ? acca[i+8] : acca[i];
        r8a[i] = kpa + __shfl_xor(sna, 32);
        float snb  = b5 ? accb[i]   : accb[i+8];
        float kpb  = b5 ? accb[i+8] : accb[i];
        r8b[i] = kpb + __shfl_xor(snb, 32);
    }
    const bool b4 = (lane & 16) != 0;
    float r4a[4], r4b[4];
#pragma unroll
    for(int i=0;i<4;i++){
        float sna  = b4 ? r8a[i]   : r8a[i+4];
        float kpa  = b4 ? r8a[i+4] : r8a[i];
        r4a[i] = kpa + __shfl_xor(sna, 16);
        float snb  = b4 ? r8b[i]   : r8b[i+4];
        float kpb  = b4 ? r8b[i+4] : r8b[i];
        r4b[i] = kpb + __shfl_xor(snb, 16);
    }
    const bool b3 = (lane & 8) != 0;
    float r2a[2], r2b[2];
#pragma unroll
    for(int i=0;i<2;i++){
        float sna  = b3 ? r4a[i]   : r4a[i+2];
        float kpa  = b3 ? r4a[i+2] : r4a[i];
        r2a[i] = kpa + __shfl_xor(sna, 8);
        float snb  = b3 ? r4b[i]   : r4b[i+2];
        float kpb  = b3 ? r4b[i+2] : r4b[i];
        r2b[i] = kpb + __shfl_xor(snb, 8);
    }
    const bool b2 = (lane & 4) != 0;
    {
        float sna  = b2 ? r2a[0] : r2a[1];
        float kpa  = b2 ? r2a[1] : r2a[0];
        r2a[0] = kpa + __shfl_xor(sna, 4);
        float snb  = b2 ? r2b[0] : r2b[1];
        float kpb  = b2 ? r2b[1] : r2b[0];
        r2b[0] = kpb + __shfl_xor(snb, 4);
    }
    r2a[0] += __shfl_xor(r2a[0], 2);  r2b[0] += __shfl_xor(r2b[0], 2);
    r2a[0] += __shfl_xor(r2a[0], 1);  r2b[0] += __shfl_xor(r2b[0], 1);

    float inva = 1.0f/suma, invb = 1.0f/sumb;
    if ((lane&3)==0){
        int d = lane>>2;
        msg2[((size_t)bh*N2+qbase  )*16 + d] = r2a[0]*inva;
        msg2[((size_t)bh*N2+qbase+1)*16 + d] = r2b[0]*invb;
    }

    // top-16 for both queries, interleaved (ties -> lowest index)
    int* ipa = idx2 + ((size_t)bh*N2+qbase  )*16;
    int* ipb = idx2 + ((size_t)bh*N2+qbase+1)*16;
    for(int it=0; it<16; it++){
        float bva = eva[0]; int bta=0;
        float bvb = evb[0]; int btb=0;
#pragma unroll
        for(int t9=1;t9<9;t9++){
            if (eva[t9] > bva){ bva=eva[t9]; bta=t9; }
            if (evb[t9] > bvb){ bvb=evb[t9]; btb=t9; }
        }
        int bma = bta*64 + lane;
        int bmb = btb*64 + lane;
#pragma unroll
        for(int st=1; st<64; st<<=1){
            float ova = __shfl_xor(bva, st);
            int   oma = __shfl_xor(bma, st);
            if (ova > bva || (ova==bva && oma < bma)){ bva=ova; bma=oma; }
            float ovb = __shfl_xor(bvb, st);
            int   omb = __shfl_xor(bmb, st);
            if (ovb > bvb || (ovb==bvb && omb < bmb)){ bvb=ovb; bmb=omb; }
        }
        if (lane==0){ ipa[it] = bma; ipb[it] = bmb; }
        int bt9a = bma>>6, bt9b = bmb>>6;
#pragma unroll
        for(int t9=0;t9<9;t9++){
            if (t9==bt9a && (bma & 63) == lane) eva[t9] = -1e30f;
            if (t9==bt9b && (bmb & 63) == lane) evb[t9] = -1e30f;
        }
    }
}

// ---------------- level-1 refinement (64 candidates/query) + rank-based top-8 ----------------
__global__ __launch_bounds__(256) void k_ref1(const float* __restrict__ q1, const float* __restrict__ k1,
    const float* __restrict__ v1, const float* __restrict__ msg2, const int* __restrict__ idx2,
    float* __restrict__ msg1, int* __restrict__ idx1)
{
    const int gw = blockIdx.x*4 + (threadIdx.x>>6);
    const int lane = threadIdx.x & 63;
    const int bh = gw / N1, n = gw - bh*N1;
    const int y = n / W1_, x = n - y*W1_;
    const int par = (y>>1)*W2_ + (x>>1);
    const int kk = lane>>2, tt = lane&3, dy = tt>>1, dx = tt&1;
    int p = idx2[((size_t)bh*N2+par)*16 + kk];
    int ky = p / W2_, kx = p - ky*W2_;
    int child = (2*ky+dy)*W1_ + 2*kx+dx;

    const float* qp = q1 + ((size_t)bh*N1+n)*16;
    float qr[16];
#pragma unroll
    for(int d=0; d<16; d+=4){
        float4 qq = *(const float4*)(qp+d);
        qr[d]=qq.x; qr[d+1]=qq.y; qr[d+2]=qq.z; qr[d+3]=qq.w;
    }
    const float4* kp = (const float4*)(k1 + ((size_t)bh*N1+child)*16);
    float s = 0.f;
#pragma unroll
    for(int dq=0;dq<4;dq++){
        float4 kv = kp[dq];
        s += qr[dq*4+0]*kv.x + qr[dq*4+1]*kv.y + qr[dq*4+2]*kv.z + qr[dq*4+3]*kv.w;
    }
    s *= TEMP;
    float e = expf(s);
    float sum = e;
#pragma unroll
    for(int st=1; st<64; st<<=1) sum += __shfl_xor(sum, st);

    float acc[16];
    const float4* vp = (const float4*)(v1 + ((size_t)bh*N1+child)*16);
#pragma unroll
    for(int dq=0;dq<4;dq++){
        float4 vv = vp[dq];
        acc[dq*4+0]=e*vv.x; acc[dq*4+1]=e*vv.y; acc[dq*4+2]=e*vv.z; acc[dq*4+3]=e*vv.w;
    }
    const bool b5 = (lane & 32) != 0;
    float r8[8];
#pragma unroll
    for(int i=0;i<8;i++){
        float snd  = b5 ? acc[i]   : acc[i+8];
        float kept = b5 ? acc[i+8] : acc[i];
        r8[i] = kept + __shfl_xor(snd, 32);
    }
    const bool b4 = (lane & 16) != 0;
    float r4[4];
#pragma unroll
    for(int i=0;i<4;i++){
        float snd  = b4 ? r8[i]   : r8[i+4];
        float kept = b4 ? r8[i+4] : r8[i];
        r4[i] = kept + __shfl_xor(snd, 16);
    }
    const bool b3 = (lane & 8) != 0;
    float r2[2];
#pragma unroll
    for(int i=0;i<2;i++){
        float snd  = b3 ? r4[i]   : r4[i+2];
        float kept = b3 ? r4[i+2] : r4[i];
        r2[i] = kept + __shfl_xor(snd, 8);
    }
    const bool b2 = (lane & 4) != 0;
    {
        float snd  = b2 ? r2[0] : r2[1];
        float kept = b2 ? r2[1] : r2[0];
        r2[0] = kept + __shfl_xor(snd, 4);
    }
    r2[0] += __shfl_xor(r2[0], 2);
    r2[0] += __shfl_xor(r2[0], 1);

    float inv = 1.0f/sum;
    if ((lane&3)==0){
        int d = lane>>2;
        msg1[((size_t)bh*N1+n)*16 + d] =
            msg2[((size_t)bh*N2+par)*16 + d] + r2[0]*inv;
    }

    // rank-based top-8 (stable: ties -> lowest candidate position)
    int cnt = 0;
#pragma unroll
    for(int i=0;i<64;i++){
        float si = __shfl(s, i);
        if (si > s || (si == s && i < lane)) cnt++;
    }
    if (cnt < 8) idx1[((size_t)bh*N1+n)*8 + cnt] = child;
}

// ---------------- level-0 refinement (32 candidates/query), 2 queries per wave ----------------
__global__ __launch_bounds__(256) void k_ref0(const float* __restrict__ q0, const float* __restrict__ k0,
    const float* __restrict__ v0, const float* __restrict__ msg1, const int* __restrict__ idx1,
    float* __restrict__ msg0)
{
    const int gw = blockIdx.x*4 + (threadIdx.x>>6);
    const int lane = threadIdx.x & 63;
    const int sub = lane>>5, j = lane&31;
    const int qi = gw*2 + sub;
    const int bh = qi / N0, n = qi - bh*N0;
    const int y = n / W0_, x = n - y*W0_;
    const int par = (y>>1)*W1_ + (x>>1);
    const int kk = j>>2, tt = j&3, dy = tt>>1, dx = tt&1;
    int p = idx1[((size_t)bh*N1+par)*8 + kk];
    int ky = p / W1_, kx = p - ky*W1_;
    int child = (2*ky+dy)*W0_ + 2*kx+dx;

    const float* qp = q0 + ((size_t)bh*N0+n)*16;
    float qr[16];
#pragma unroll
    for(int d=0; d<16; d+=4){
        float4 qq = *(const float4*)(qp+d);
        qr[d]=qq.x; qr[d+1]=qq.y; qr[d+2]=qq.z; qr[d+3]=qq.w;
    }
    const float4* kp = (const float4*)(k0 + ((size_t)bh*N0+child)*16);
    float s = 0.f;
#pragma unroll
    for(int dq=0;dq<4;dq++){
        float4 kv = kp[dq];
        s += qr[dq*4+0]*kv.x + qr[dq*4+1]*kv.y + qr[dq*4+2]*kv.z + qr[dq*4+3]*kv.w;
    }
    s *= TEMP;
    float e = expf(s);
    float sum = e;
#pragma unroll
    for(int st=1; st<32; st<<=1) sum += __shfl_xor(sum, st);

    float acc[16];
    const float4* vp = (const float4*)(v0 + ((size_t)bh*N0+child)*16);
#pragma unroll
    for(int dq=0;dq<4;dq++){
        float4 vv = vp[dq];
        acc[dq*4+0]=e*vv.x; acc[dq*4+1]=e*vv.y; acc[dq*4+2]=e*vv.z; acc[dq*4+3]=e*vv.w;
    }
    const bool b4 = (j & 16) != 0;
    float r8[8];
#pragma unroll
    for(int i=0;i<8;i++){
        float snd  = b4 ? acc[i]   : acc[i+8];
        float kept = b4 ? acc[i+8] : acc[i];
        r8[i] = kept + __shfl_xor(snd, 16);
    }
    const bool b3 = (j & 8) != 0;
    float r4[4];
#pragma unroll
    for(int i=0;i<4;i++){
        float snd  = b3 ? r8[i]   : r8[i+4];
        float kept = b3 ? r8[i+4] : r8[i];
        r4[i] = kept + __shfl_xor(snd, 8);
    }
    const bool b2 = (j & 4) != 0;
    float r2[2];
#pragma unroll
    for(int i=0;i<2;i++){
        float snd  = b2 ? r4[i]   : r4[i+2];
        float kept = b2 ? r4[i+2] : r4[i];
        r2[i] = kept + __shfl_xor(snd, 4);
    }
    const bool b1 = (j & 2) != 0;
    {
        float snd  = b1 ? r2[0] : r2[1];
        float kept = b1 ? r2[1] : r2[0];
        r2[0] = kept + __shfl_xor(snd, 2);
    }
    r2[0] += __shfl_xor(r2[0], 1);

    float inv = 1.0f/sum;
    if ((j&1)==0){
        int d = j>>1;
        int b_ = bh>>3, h = bh&7;
        msg0[((size_t)b_*N0+n)*128 + h*16 + d] =
            msg1[((size_t)bh*N1+par)*16 + d] + r2[0]*inv;
    }
}

// ---------------- output projection GEMM + bias ----------------
__global__ __launch_bounds__(256) void k_out(const float* __restrict__ msg0, const float* __restrict__ Wo,
    const float* __restrict__ bo, float* __restrict__ out)
{
    __shared__ __align__(16) float At[16][68];
    __shared__ __align__(16) float Wt[16][132];
    const int t = threadIdx.x;
    const int m0 = blockIdx.x * 64;
    const int tx = t & 15, ty = t >> 4;

    float acc[4][8];
#pragma unroll
    for(int i=0;i<4;i++)
#pragma unroll
        for(int j=0;j<8;j++) acc[i][j]=0.f;

    const int ar = t>>2, akq = (t&3)*4;
    const int wo = t>>1, wkq = (t&1)*8;

    for(int kc=0;kc<128;kc+=16){
        float4 av = *(const float4*)(msg0 + (size_t)(m0+ar)*128 + kc + akq);
        At[akq+0][ar] = av.x;
        At[akq+1][ar] = av.y;
        At[akq+2][ar] = av.z;
        At[akq+3][ar] = av.w;
        float4 w0 = *(const float4*)(Wo + (size_t)wo*128 + kc + wkq);
        float4 w1 = *(const float4*)(Wo + (size_t)wo*128 + kc + wkq + 4);
        Wt[wkq+0][wo] = w0.x; Wt[wkq+1][wo] = w0.y;
        Wt[wkq+2][wo] = w0.z; Wt[wkq+3][wo] = w0.w;
        Wt[wkq+4][wo] = w1.x; Wt[wkq+5][wo] = w1.y;
        Wt[wkq+6][wo] = w1.z; Wt[wkq+7][wo] = w1.w;
        __syncthreads();
#pragma unroll
        for(int kk=0;kk<16;kk++){
            float4 a4 = *(const float4*)&At[kk][ty*4];
            float4 wa = *(const float4*)&Wt[kk][tx*4];
            float4 wb = *(const float4*)&Wt[kk][64 + tx*4];
            float avr[4] = {a4.x,a4.y,a4.z,a4.w};
            float wvr[8] = {wa.x,wa.y,wa.z,wa.w, wb.x,wb.y,wb.z,wb.w};
#pragma unroll
            for(int i=0;i<4;i++)
#pragma unroll
                for(int j=0;j<8;j++) acc[i][j] += avr[i]*wvr[j];
        }
        __syncthreads();
    }
#pragma unroll
    for(int i=0;i<4;i++){
        int m = m0 + ty*4 + i;
#pragma unroll
        for(int j=0;j<8;j++){
            int o = (j<4)? (tx*4+j) : (64 + tx*4 + (j-4));
            out[(size_t)m*128 + o] = acc[i][j] + bo[o];
        }
    }
}

extern "C" void kernel_launch(void* const* d_in, const int* in_sizes, int n_in,
                              void* d_out, int out_size, void* d_ws, size_t ws_size,
                              hipStream_t stream) {
    const float* x  = (const float*)d_in[0];
    const float* tg = (const float*)d_in[1];
    const float* Wq = (const float*)d_in[2];
    const float* Wk = (const float*)d_in[3];
    const float* Wv = (const float*)d_in[4];
    const float* Wo = (const float*)d_in[5];
    const float* bo = (const float*)d_in[6];

    float* ws = (float*)d_ws;
    float* q0   = ws + 0;
    float* k0   = ws + 2359296;
    float* v0   = ws + 4718592;
    float* q1   = ws + 7077888;
    float* k1   = ws + 7667712;
    float* v1   = ws + 8257536;
    float* q2   = ws + 8847360;
    float* k2   = ws + 8994816;
    float* v2   = ws + 9142272;
    float* msg2 = ws + 9289728;
    float* msg1 = ws + 9437184;
    float* msg0 = ws + 10027008;
    int*   idx2 = (int*)(ws + 12386304);
    int*   idx1 = (int*)(ws + 12533760);

    k_proj<<<dim3(288,3), 256, 0, stream>>>(x, tg, Wq, Wk, Wv, q0, k0, v0);
    k_pool<<<442368/256, 256, 0, stream>>>((const float4*)q0, (float4*)q1, 96, N0, N1, 442368);
    k_pool<<<110592/256, 256, 0, stream>>>((const float4*)q1, (float4*)q2, 48, N1, N2, 110592);
    k_attn2<<<dim3(16,72), 256, 0, stream>>>(q2, k2, v2, msg2, idx2);
    k_ref1<<<9216, 256, 0, stream>>>(q1, k1, v1, msg2, idx2, msg1, idx1);
    k_ref0<<<18432, 256, 0, stream>>>(q0, k0, v0, msg1, idx1, msg0);
    k_out<<<288, 256, 0, stream>>>(msg0, Wo, bo, (float*)d_out);
}

// Round 7
// 288.426 us; speedup vs baseline: 1.0237x; 1.0237x over previous
//
#include <hip/hip_runtime.h>

#define NB   2
#define NHD  8
#define BH   16
#define HD   16
#define N0   9216
#define N1   2304
#define N2   576
#define W0_  96
#define W1_  48
#define W2_  24
#define M_TOT 18432
#define TEMP 0.25f

// ---------------- projection GEMM: dst[(b,h,n,d)] = sum_c A[m][c] * W[o][c] ----------------
__global__ __launch_bounds__(256) void k_proj(const float* __restrict__ x, const float* __restrict__ tg,
    const float* __restrict__ Wq, const float* __restrict__ Wk, const float* __restrict__ Wv,
    float* __restrict__ q0, float* __restrict__ k0, float* __restrict__ v0)
{
    __shared__ __align__(16) float At[16][68];   // [k][row]
    __shared__ __align__(16) float Wt[16][132];  // [k][o]
    const int t = threadIdx.x;
    const int which = blockIdx.y;
    const float* A  = (which==0)? x : tg;
    const float* Wm = (which==0)? Wq : (which==1? Wk : Wv);
    float* dst      = (which==0)? q0 : (which==1? k0 : v0);
    const int m0 = blockIdx.x * 64;
    const int tx = t & 15, ty = t >> 4;

    float acc[4][8];
#pragma unroll
    for(int i=0;i<4;i++)
#pragma unroll
        for(int j=0;j<8;j++) acc[i][j]=0.f;

    const int ar = t>>2, akq = (t&3)*4;
    const int wo = t>>1, wkq = (t&1)*8;

    for(int kc=0;kc<128;kc+=16){
        float4 av = *(const float4*)(A + (size_t)(m0+ar)*128 + kc + akq);
        At[akq+0][ar] = av.x;
        At[akq+1][ar] = av.y;
        At[akq+2][ar] = av.z;
        At[akq+3][ar] = av.w;
        float4 w0 = *(const float4*)(Wm + (size_t)wo*128 + kc + wkq);
        float4 w1 = *(const float4*)(Wm + (size_t)wo*128 + kc + wkq + 4);
        Wt[wkq+0][wo] = w0.x; Wt[wkq+1][wo] = w0.y;
        Wt[wkq+2][wo] = w0.z; Wt[wkq+3][wo] = w0.w;
        Wt[wkq+4][wo] = w1.x; Wt[wkq+5][wo] = w1.y;
        Wt[wkq+6][wo] = w1.z; Wt[wkq+7][wo] = w1.w;
        __syncthreads();
#pragma unroll
        for(int kk=0;kk<16;kk++){
            float4 a4 = *(const float4*)&At[kk][ty*4];
            float4 wa = *(const float4*)&Wt[kk][tx*4];
            float4 wb = *(const float4*)&Wt[kk][64 + tx*4];
            float avr[4] = {a4.x,a4.y,a4.z,a4.w};
            float wvr[8] = {wa.x,wa.y,wa.z,wa.w, wb.x,wb.y,wb.z,wb.w};
#pragma unroll
            for(int i=0;i<4;i++)
#pragma unroll
                for(int j=0;j<8;j++) acc[i][j] += avr[i]*wvr[j];
        }
        __syncthreads();
    }
#pragma unroll
    for(int i=0;i<4;i++){
        int m = m0 + ty*4 + i;
        int b = m / N0; int n = m - b*N0;
#pragma unroll
        for(int j=0;j<8;j++){
            int o = (j<4)? (tx*4+j) : (64 + tx*4 + (j-4));
            int h = o>>4, d = o&15;
            dst[((size_t)(b*NHD+h)*N0 + n)*16 + d] = acc[i][j];
        }
    }
}

// ---------------- 2x2 average pooling, treats q/k/v contiguously as [48][Nin][16] ----------------
__global__ __launch_bounds__(256) void k_pool(const float4* __restrict__ src, float4* __restrict__ dst,
                                              int Win, int Nin, int Nout, int total)
{
    int tid = blockIdx.x*256 + threadIdx.x;
    if (tid >= total) return;
    int d4 = tid & 3;
    int rest = tid >> 2;
    int n = rest % Nout; int g = rest / Nout;
    int Wout = Win>>1;
    int yo = n / Wout, xo = n - yo*Wout;
    int cbase = (2*yo)*Win + 2*xo;
    const float4* s = src + (size_t)g*Nin*4;
    float4 a = s[(cbase      )*4 + d4];
    float4 b = s[(cbase+1    )*4 + d4];
    float4 c = s[(cbase+Win  )*4 + d4];
    float4 d = s[(cbase+Win+1)*4 + d4];
    float4 o;
    o.x = 0.25f*(a.x+b.x+c.x+d.x);
    o.y = 0.25f*(a.y+b.y+c.y+d.y);
    o.z = 0.25f*(a.z+b.z+c.z+d.z);
    o.w = 0.25f*(a.w+b.w+c.w+d.w);
    dst[((size_t)g*Nout + n)*4 + d4] = o;
}

// ---- level-2 full attention + top-16: LDS-free, 1 query/wave, presorted top-16 ----
__global__ __launch_bounds__(256) void k_attn2(const float* __restrict__ q2, const float* __restrict__ k2,
    const float* __restrict__ v2, float* __restrict__ msg2, int* __restrict__ idx2)
{
    const int bh = blockIdx.x;
    const int wv = threadIdx.x>>6, lane = threadIdx.x&63;
    const int q = blockIdx.y*4 + wv;   // one query per wave

    float qr[16];
    const float4* qp = (const float4*)(q2 + ((size_t)bh*N2 + q)*16);
#pragma unroll
    for(int dq=0;dq<4;dq++){
        float4 va = qp[dq];
        qr[dq*4+0]=va.x; qr[dq*4+1]=va.y; qr[dq*4+2]=va.z; qr[dq*4+3]=va.w;
    }

    const float4* kg = (const float4*)(k2 + (size_t)bh*N2*16);
    const float4* vg = (const float4*)(v2 + (size_t)bh*N2*16);

    // pass 1: scores + running max (bit-identical order to prior passing kernel)
    float ev[9];
    float mx = -1e30f;
#pragma unroll
    for(int t9=0;t9<9;t9++){
        int m = t9*64 + lane;
        float kr[16];
#pragma unroll
        for(int dq=0;dq<4;dq++){
            float4 kv = kg[m*4+dq];
            kr[dq*4+0]=kv.x; kr[dq*4+1]=kv.y; kr[dq*4+2]=kv.z; kr[dq*4+3]=kv.w;
        }
        float s = 0.f;
#pragma unroll
        for(int d=0;d<16;d++) s += qr[d]*kr[d];
        s *= TEMP;
        ev[t9]=s;
        mx = fmaxf(mx, s);
    }
#pragma unroll
    for(int st=1; st<64; st<<=1) mx = fmaxf(mx, __shfl_xor(mx, st));

    // pass 2: exp(s-mx), sum, P·V
    float sum=0.f;
    float acc[16];
#pragma unroll
    for(int d=0;d<16;d++) acc[d]=0.f;
#pragma unroll
    for(int t9=0;t9<9;t9++){
        int m = t9*64 + lane;
        float e = expf(ev[t9]-mx);
        ev[t9]=e;
        sum += e;
        float vr[16];
#pragma unroll
        for(int dq=0;dq<4;dq++){
            float4 vv = vg[m*4+dq];
            vr[dq*4+0]=vv.x; vr[dq*4+1]=vv.y; vr[dq*4+2]=vv.z; vr[dq*4+3]=vv.w;
        }
#pragma unroll
        for(int d=0;d<16;d++) acc[d] += e*vr[d];
    }
#pragma unroll
    for(int st=1; st<64; st<<=1) sum += __shfl_xor(sum, st);

    // dim-splitting butterfly: lane ends with O[lane>>2]
    const bool b5 = (lane & 32) != 0;
    float r8[8];
#pragma unroll
    for(int i=0;i<8;i++){
        float snd  = b5 ? acc[i]   : acc[i+8];
        float kept = b5 ? acc[i+8] : acc[i];
        r8[i] = kept + __shfl_xor(snd, 32);
    }
    const bool b4 = (lane & 16) != 0;
    float r4[4];
#pragma unroll
    for(int i=0;i<4;i++){
        float snd  = b4 ? r8[i]   : r8[i+4];
        float kept = b4 ? r8[i+4] : r8[i];
        r4[i] = kept + __shfl_xor(snd, 16);
    }
    const bool b3 = (lane & 8) != 0;
    float r2[2];
#pragma unroll
    for(int i=0;i<2;i++){
        float snd  = b3 ? r4[i]   : r4[i+2];
        float kept = b3 ? r4[i+2] : r4[i];
        r2[i] = kept + __shfl_xor(snd, 8);
    }
    const bool b2 = (lane & 4) != 0;
    {
        float snd  = b2 ? r2[0] : r2[1];
        float kept = b2 ? r2[1] : r2[0];
        r2[0] = kept + __shfl_xor(snd, 4);
    }
    r2[0] += __shfl_xor(r2[0], 2);
    r2[0] += __shfl_xor(r2[0], 1);

    float inv = 1.0f/sum;
    if ((lane&3)==0){
        msg2[((size_t)bh*N2+q)*16 + (lane>>2)] = r2[0]*inv;
    }

    // ---- top-16: presort each lane's 9 values (stable desc by (val, idx asc)), then pop heads ----
    int id[9];
#pragma unroll
    for(int i=0;i<9;i++) id[i]=i;
#pragma unroll
    for(int p=0;p<8;p++){
#pragma unroll
        for(int i=0;i<8-p;i++){
            bool sw = (ev[i+1] > ev[i]) || (ev[i+1]==ev[i] && id[i+1]<id[i]);
            float tv = sw? ev[i+1]:ev[i]; float bv2 = sw? ev[i]:ev[i+1];
            int   ti = sw? id[i+1]:id[i]; int   bi  = sw? id[i]:id[i+1];
            ev[i]=tv; ev[i+1]=bv2; id[i]=ti; id[i+1]=bi;
        }
    }
    int* ip = idx2 + ((size_t)bh*N2+q)*16;
    for(int it=0; it<16; it++){
        float bv = ev[0];
        int   bm = id[0]*64 + lane;
#pragma unroll
        for(int st=1; st<64; st<<=1){
            float ov = __shfl_xor(bv, st);
            int   om = __shfl_xor(bm, st);
            if (ov > bv || (ov==bv && om < bm)){ bv=ov; bm=om; }
        }
        if (lane==0) ip[it] = bm;
        if ((bm & 63) == lane){
#pragma unroll
            for(int i=0;i<8;i++){ ev[i]=ev[i+1]; id[i]=id[i+1]; }
            ev[8] = -1e30f;
        }
    }
}

// ---------------- level-1 refinement (64 candidates/query) + rank-based top-8 ----------------
__global__ __launch_bounds__(256) void k_ref1(const float* __restrict__ q1, const float* __restrict__ k1,
    const float* __restrict__ v1, const float* __restrict__ msg2, const int* __restrict__ idx2,
    float* __restrict__ msg1, int* __restrict__ idx1)
{
    const int gw = blockIdx.x*4 + (threadIdx.x>>6);
    const int lane = threadIdx.x & 63;
    const int bh = gw / N1, n = gw - bh*N1;
    const int y = n / W1_, x = n - y*W1_;
    const int par = (y>>1)*W2_ + (x>>1);
    const int kk = lane>>2, tt = lane&3, dy = tt>>1, dx = tt&1;
    int p = idx2[((size_t)bh*N2+par)*16 + kk];
    int ky = p / W2_, kx = p - ky*W2_;
    int child = (2*ky+dy)*W1_ + 2*kx+dx;

    const float* qp = q1 + ((size_t)bh*N1+n)*16;
    float qr[16];
#pragma unroll
    for(int d=0; d<16; d+=4){
        float4 qq = *(const float4*)(qp+d);
        qr[d]=qq.x; qr[d+1]=qq.y; qr[d+2]=qq.z; qr[d+3]=qq.w;
    }
    const float4* kp = (const float4*)(k1 + ((size_t)bh*N1+child)*16);
    float s = 0.f;
#pragma unroll
    for(int dq=0;dq<4;dq++){
        float4 kv = kp[dq];
        s += qr[dq*4+0]*kv.x + qr[dq*4+1]*kv.y + qr[dq*4+2]*kv.z + qr[dq*4+3]*kv.w;
    }
    s *= TEMP;
    float e = expf(s);
    float sum = e;
#pragma unroll
    for(int st=1; st<64; st<<=1) sum += __shfl_xor(sum, st);

    float acc[16];
    const float4* vp = (const float4*)(v1 + ((size_t)bh*N1+child)*16);
#pragma unroll
    for(int dq=0;dq<4;dq++){
        float4 vv = vp[dq];
        acc[dq*4+0]=e*vv.x; acc[dq*4+1]=e*vv.y; acc[dq*4+2]=e*vv.z; acc[dq*4+3]=e*vv.w;
    }
    const bool b5 = (lane & 32) != 0;
    float r8[8];
#pragma unroll
    for(int i=0;i<8;i++){
        float snd  = b5 ? acc[i]   : acc[i+8];
        float kept = b5 ? acc[i+8] : acc[i];
        r8[i] = kept + __shfl_xor(snd, 32);
    }
    const bool b4 = (lane & 16) != 0;
    float r4[4];
#pragma unroll
    for(int i=0;i<4;i++){
        float snd  = b4 ? r8[i]   : r8[i+4];
        float kept = b4 ? r8[i+4] : r8[i];
        r4[i] = kept + __shfl_xor(snd, 16);
    }
    const bool b3 = (lane & 8) != 0;
    float r2[2];
#pragma unroll
    for(int i=0;i<2;i++){
        float snd  = b3 ? r4[i]   : r4[i+2];
        float kept = b3 ? r4[i+2] : r4[i];
        r2[i] = kept + __shfl_xor(snd, 8);
    }
    const bool b2 = (lane & 4) != 0;
    {
        float snd  = b2 ? r2[0] : r2[1];
        float kept = b2 ? r2[1] : r2[0];
        r2[0] = kept + __shfl_xor(snd, 4);
    }
    r2[0] += __shfl_xor(r2[0], 2);
    r2[0] += __shfl_xor(r2[0], 1);

    float inv = 1.0f/sum;
    if ((lane&3)==0){
        int d = lane>>2;
        msg1[((size_t)bh*N1+n)*16 + d] =
            msg2[((size_t)bh*N2+par)*16 + d] + r2[0]*inv;
    }

    // rank-based top-8 (stable: ties -> lowest candidate position)
    int cnt = 0;
#pragma unroll
    for(int i=0;i<64;i++){
        float si = __shfl(s, i);
        if (si > s || (si == s && i < lane)) cnt++;
    }
    if (cnt < 8) idx1[((size_t)bh*N1+n)*8 + cnt] = child;
}

// ---------------- level-0 refinement (32 candidates/query), 2 queries per wave ----------------
__global__ __launch_bounds__(256) void k_ref0(const float* __restrict__ q0, const float* __restrict__ k0,
    const float* __restrict__ v0, const float* __restrict__ msg1, const int* __restrict__ idx1,
    float* __restrict__ msg0)
{
    const int gw = blockIdx.x*4 + (threadIdx.x>>6);
    const int lane = threadIdx.x & 63;
    const int sub = lane>>5, j = lane&31;
    const int qi = gw*2 + sub;
    const int bh = qi / N0, n = qi - bh*N0;
    const int y = n / W0_, x = n - y*W0_;
    const int par = (y>>1)*W1_ + (x>>1);
    const int kk = j>>2, tt = j&3, dy = tt>>1, dx = tt&1;
    int p = idx1[((size_t)bh*N1+par)*8 + kk];
    int ky = p / W1_, kx = p - ky*W1_;
    int child = (2*ky+dy)*W0_ + 2*kx+dx;

    const float* qp = q0 + ((size_t)bh*N0+n)*16;
    float qr[16];
#pragma unroll
    for(int d=0; d<16; d+=4){
        float4 qq = *(const float4*)(qp+d);
        qr[d]=qq.x; qr[d+1]=qq.y; qr[d+2]=qq.z; qr[d+3]=qq.w;
    }
    const float4* kp = (const float4*)(k0 + ((size_t)bh*N0+child)*16);
    float s = 0.f;
#pragma unroll
    for(int dq=0;dq<4;dq++){
        float4 kv = kp[dq];
        s += qr[dq*4+0]*kv.x + qr[dq*4+1]*kv.y + qr[dq*4+2]*kv.z + qr[dq*4+3]*kv.w;
    }
    s *= TEMP;
    float e = expf(s);
    float sum = e;
#pragma unroll
    for(int st=1; st<32; st<<=1) sum += __shfl_xor(sum, st);

    float acc[16];
    const float4* vp = (const float4*)(v0 + ((size_t)bh*N0+child)*16);
#pragma unroll
    for(int dq=0;dq<4;dq++){
        float4 vv = vp[dq];
        acc[dq*4+0]=e*vv.x; acc[dq*4+1]=e*vv.y; acc[dq*4+2]=e*vv.z; acc[dq*4+3]=e*vv.w;
    }
    const bool b4 = (j & 16) != 0;
    float r8[8];
#pragma unroll
    for(int i=0;i<8;i++){
        float snd  = b4 ? acc[i]   : acc[i+8];
        float kept = b4 ? acc[i+8] : acc[i];
        r8[i] = kept + __shfl_xor(snd, 16);
    }
    const bool b3 = (j & 8) != 0;
    float r4[4];
#pragma unroll
    for(int i=0;i<4;i++){
        float snd  = b3 ? r8[i]   : r8[i+4];
        float kept = b3 ? r8[i+4] : r8[i];
        r4[i] = kept + __shfl_xor(snd, 8);
    }
    const bool b2 = (j & 4) != 0;
    float r2[2];
#pragma unroll
    for(int i=0;i<2;i++){
        float snd  = b2 ? r4[i]   : r4[i+2];
        float kept = b2 ? r4[i+2] : r4[i];
        r2[i] = kept + __shfl_xor(snd, 4);
    }
    const bool b1 = (j & 2) != 0;
    {
        float snd  = b1 ? r2[0] : r2[1];
        float kept = b1 ? r2[1] : r2[0];
        r2[0] = kept + __shfl_xor(snd, 2);
    }
    r2[0] += __shfl_xor(r2[0], 1);

    float inv = 1.0f/sum;
    if ((j&1)==0){
        int d = j>>1;
        int b_ = bh>>3, h = bh&7;
        msg0[((size_t)b_*N0+n)*128 + h*16 + d] =
            msg1[((size_t)bh*N1+par)*16 + d] + r2[0]*inv;
    }
}

// ---------------- output projection GEMM + bias ----------------
__global__ __launch_bounds__(256) void k_out(const float* __restrict__ msg0, const float* __restrict__ Wo,
    const float* __restrict__ bo, float* __restrict__ out)
{
    __shared__ __align__(16) float At[16][68];
    __shared__ __align__(16) float Wt[16][132];
    const int t = threadIdx.x;
    const int m0 = blockIdx.x * 64;
    const int tx = t & 15, ty = t >> 4;

    float acc[4][8];
#pragma unroll
    for(int i=0;i<4;i++)
#pragma unroll
        for(int j=0;j<8;j++) acc[i][j]=0.f;

    const int ar = t>>2, akq = (t&3)*4;
    const int wo = t>>1, wkq = (t&1)*8;

    for(int kc=0;kc<128;kc+=16){
        float4 av = *(const float4*)(msg0 + (size_t)(m0+ar)*128 + kc + akq);
        At[akq+0][ar] = av.x;
        At[akq+1][ar] = av.y;
        At[akq+2][ar] = av.z;
        At[akq+3][ar] = av.w;
        float4 w0 = *(const float4*)(Wo + (size_t)wo*128 + kc + wkq);
        float4 w1 = *(const float4*)(Wo + (size_t)wo*128 + kc + wkq + 4);
        Wt[wkq+0][wo] = w0.x; Wt[wkq+1][wo] = w0.y;
        Wt[wkq+2][wo] = w0.z; Wt[wkq+3][wo] = w0.w;
        Wt[wkq+4][wo] = w1.x; Wt[wkq+5][wo] = w1.y;
        Wt[wkq+6][wo] = w1.z; Wt[wkq+7][wo] = w1.w;
        __syncthreads();
#pragma unroll
        for(int kk=0;kk<16;kk++){
            float4 a4 = *(const float4*)&At[kk][ty*4];
            float4 wa = *(const float4*)&Wt[kk][tx*4];
            float4 wb = *(const float4*)&Wt[kk][64 + tx*4];
            float avr[4] = {a4.x,a4.y,a4.z,a4.w};
            float wvr[8] = {wa.x,wa.y,wa.z,wa.w, wb.x,wb.y,wb.z,wb.w};
#pragma unroll
            for(int i=0;i<4;i++)
#pragma unroll
                for(int j=0;j<8;j++) acc[i][j] += avr[i]*wvr[j];
        }
        __syncthreads();
    }
#pragma unroll
    for(int i=0;i<4;i++){
        int m = m0 + ty*4 + i;
#pragma unroll
        for(int j=0;j<8;j++){
            int o = (j<4)? (tx*4+j) : (64 + tx*4 + (j-4));
            out[(size_t)m*128 + o] = acc[i][j] + bo[o];
        }
    }
}

extern "C" void kernel_launch(void* const* d_in, const int* in_sizes, int n_in,
                              void* d_out, int out_size, void* d_ws, size_t ws_size,
                              hipStream_t stream) {
    const float* x  = (const float*)d_in[0];
    const float* tg = (const float*)d_in[1];
    const float* Wq = (const float*)d_in[2];
    const float* Wk = (const float*)d_in[3];
    const float* Wv = (const float*)d_in[4];
    const float* Wo = (const float*)d_in[5];
    const float* bo = (const float*)d_in[6];

    float* ws = (float*)d_ws;
    float* q0   = ws + 0;
    float* k0   = ws + 2359296;
    float* v0   = ws + 4718592;
    float* q1   = ws + 7077888;
    float* k1   = ws + 7667712;
    float* v1   = ws + 8257536;
    float* q2   = ws + 8847360;
    float* k2   = ws + 8994816;
    float* v2   = ws + 9142272;
    float* msg2 = ws + 9289728;
    float* msg1 = ws + 9437184;
    float* msg0 = ws + 10027008;
    int*   idx2 = (int*)(ws + 12386304);
    int*   idx1 = (int*)(ws + 12533760);

    k_proj<<<dim3(288,3), 256, 0, stream>>>(x, tg, Wq, Wk, Wv, q0, k0, v0);
    k_pool<<<442368/256, 256, 0, stream>>>((const float4*)q0, (float4*)q1, 96, N0, N1, 442368);
    k_pool<<<110592/256, 256, 0, stream>>>((const float4*)q1, (float4*)q2, 48, N1, N2, 110592);
    k_attn2<<<dim3(16,144), 256, 0, stream>>>(q2, k2, v2, msg2, idx2);
    k_ref1<<<9216, 256, 0, stream>>>(q1, k1, v1, msg2, idx2, msg1, idx1);
    k_ref0<<<18432, 256, 0, stream>>>(q0, k0, v0, msg1, idx1, msg0);
    k_out<<<288, 256, 0, stream>>>(msg0, Wo, bo, (float*)d_out);
}

// Round 8
// 276.231 us; speedup vs baseline: 1.0688x; 1.0441x over previous
//
#include <hip/hip_runtime.h>

#define NB   2
#define NHD  8
#define BH   16
#define HD   16
#define N0   9216
#define N1   2304
#define N2   576
#define W0_  96
#define W1_  48
#define W2_  24
#define M_TOT 18432
#define TEMP 0.25f

// ---------------- projection GEMM: dst[(b,h,n,d)] = sum_c A[m][c] * W[o][c] ----------------
__global__ __launch_bounds__(256) void k_proj(const float* __restrict__ x, const float* __restrict__ tg,
    const float* __restrict__ Wq, const float* __restrict__ Wk, const float* __restrict__ Wv,
    float* __restrict__ q0, float* __restrict__ k0, float* __restrict__ v0)
{
    __shared__ __align__(16) float At[16][68];   // [k][row]
    __shared__ __align__(16) float Wt[16][132];  // [k][o]
    const int t = threadIdx.x;
    const int which = blockIdx.y;
    const float* A  = (which==0)? x : tg;
    const float* Wm = (which==0)? Wq : (which==1? Wk : Wv);
    float* dst      = (which==0)? q0 : (which==1? k0 : v0);
    const int m0 = blockIdx.x * 64;
    const int tx = t & 15, ty = t >> 4;

    float acc[4][8];
#pragma unroll
    for(int i=0;i<4;i++)
#pragma unroll
        for(int j=0;j<8;j++) acc[i][j]=0.f;

    const int ar = t>>2, akq = (t&3)*4;
    const int wo = t>>1, wkq = (t&1)*8;

    for(int kc=0;kc<128;kc+=16){
        float4 av = *(const float4*)(A + (size_t)(m0+ar)*128 + kc + akq);
        At[akq+0][ar] = av.x;
        At[akq+1][ar] = av.y;
        At[akq+2][ar] = av.z;
        At[akq+3][ar] = av.w;
        float4 w0 = *(const float4*)(Wm + (size_t)wo*128 + kc + wkq);
        float4 w1 = *(const float4*)(Wm + (size_t)wo*128 + kc + wkq + 4);
        Wt[wkq+0][wo] = w0.x; Wt[wkq+1][wo] = w0.y;
        Wt[wkq+2][wo] = w0.z; Wt[wkq+3][wo] = w0.w;
        Wt[wkq+4][wo] = w1.x; Wt[wkq+5][wo] = w1.y;
        Wt[wkq+6][wo] = w1.z; Wt[wkq+7][wo] = w1.w;
        __syncthreads();
#pragma unroll
        for(int kk=0;kk<16;kk++){
            float4 a4 = *(const float4*)&At[kk][ty*4];
            float4 wa = *(const float4*)&Wt[kk][tx*4];
            float4 wb = *(const float4*)&Wt[kk][64 + tx*4];
            float avr[4] = {a4.x,a4.y,a4.z,a4.w};
            float wvr[8] = {wa.x,wa.y,wa.z,wa.w, wb.x,wb.y,wb.z,wb.w};
#pragma unroll
            for(int i=0;i<4;i++)
#pragma unroll
                for(int j=0;j<8;j++) acc[i][j] += avr[i]*wvr[j];
        }
        __syncthreads();
    }
    // vectorized epilogue: each thread's j=0..3 and j=4..7 are d-consecutive within one head
    const int hA = tx>>2, dA = (tx&3)*4;      // group A: o = tx*4+j
#pragma unroll
    for(int i=0;i<4;i++){
        int m = m0 + ty*4 + i;
        int b = m / N0; int n = m - b*N0;
        float4 sA = make_float4(acc[i][0], acc[i][1], acc[i][2], acc[i][3]);
        float4 sB = make_float4(acc[i][4], acc[i][5], acc[i][6], acc[i][7]);
        *(float4*)(dst + ((size_t)(b*NHD + hA    )*N0 + n)*16 + dA) = sA;
        *(float4*)(dst + ((size_t)(b*NHD + hA + 4)*N0 + n)*16 + dA) = sB;
    }
}

// ---------------- 2x2 average pooling, compile-time geometry ----------------
template<int Win, int Nin, int Nout, int TOTAL>
__global__ __launch_bounds__(256) void k_pool(const float4* __restrict__ src, float4* __restrict__ dst)
{
    int tid = blockIdx.x*256 + threadIdx.x;
    if (tid >= TOTAL) return;
    int d4 = tid & 3;
    int rest = tid >> 2;
    int n = rest % Nout; int g = rest / Nout;
    constexpr int Wout = Win>>1;
    int yo = n / Wout, xo = n - yo*Wout;
    int cbase = (2*yo)*Win + 2*xo;
    const float4* s = src + (size_t)g*Nin*4;
    float4 a = s[(cbase      )*4 + d4];
    float4 b = s[(cbase+1    )*4 + d4];
    float4 c = s[(cbase+Win  )*4 + d4];
    float4 d = s[(cbase+Win+1)*4 + d4];
    float4 o;
    o.x = 0.25f*(a.x+b.x+c.x+d.x);
    o.y = 0.25f*(a.y+b.y+c.y+d.y);
    o.z = 0.25f*(a.z+b.z+c.z+d.z);
    o.w = 0.25f*(a.w+b.w+c.w+d.w);
    dst[((size_t)g*Nout + n)*4 + d4] = o;
}

// ---- level-2 full attention + top-16: LDS-free, 1 query/wave, presorted top-16 (unchanged) ----
__global__ __launch_bounds__(256) void k_attn2(const float* __restrict__ q2, const float* __restrict__ k2,
    const float* __restrict__ v2, float* __restrict__ msg2, int* __restrict__ idx2)
{
    const int bh = blockIdx.x;
    const int wv = threadIdx.x>>6, lane = threadIdx.x&63;
    const int q = blockIdx.y*4 + wv;   // one query per wave

    float qr[16];
    const float4* qp = (const float4*)(q2 + ((size_t)bh*N2 + q)*16);
#pragma unroll
    for(int dq=0;dq<4;dq++){
        float4 va = qp[dq];
        qr[dq*4+0]=va.x; qr[dq*4+1]=va.y; qr[dq*4+2]=va.z; qr[dq*4+3]=va.w;
    }

    const float4* kg = (const float4*)(k2 + (size_t)bh*N2*16);
    const float4* vg = (const float4*)(v2 + (size_t)bh*N2*16);

    float ev[9];
    float mx = -1e30f;
#pragma unroll
    for(int t9=0;t9<9;t9++){
        int m = t9*64 + lane;
        float kr[16];
#pragma unroll
        for(int dq=0;dq<4;dq++){
            float4 kv = kg[m*4+dq];
            kr[dq*4+0]=kv.x; kr[dq*4+1]=kv.y; kr[dq*4+2]=kv.z; kr[dq*4+3]=kv.w;
        }
        float s = 0.f;
#pragma unroll
        for(int d=0;d<16;d++) s += qr[d]*kr[d];
        s *= TEMP;
        ev[t9]=s;
        mx = fmaxf(mx, s);
    }
#pragma unroll
    for(int st=1; st<64; st<<=1) mx = fmaxf(mx, __shfl_xor(mx, st));

    float sum=0.f;
    float acc[16];
#pragma unroll
    for(int d=0;d<16;d++) acc[d]=0.f;
#pragma unroll
    for(int t9=0;t9<9;t9++){
        int m = t9*64 + lane;
        float e = expf(ev[t9]-mx);
        ev[t9]=e;
        sum += e;
        float vr[16];
#pragma unroll
        for(int dq=0;dq<4;dq++){
            float4 vv = vg[m*4+dq];
            vr[dq*4+0]=vv.x; vr[dq*4+1]=vv.y; vr[dq*4+2]=vv.z; vr[dq*4+3]=vv.w;
        }
#pragma unroll
        for(int d=0;d<16;d++) acc[d] += e*vr[d];
    }
#pragma unroll
    for(int st=1; st<64; st<<=1) sum += __shfl_xor(sum, st);

    const bool b5 = (lane & 32) != 0;
    float r8[8];
#pragma unroll
    for(int i=0;i<8;i++){
        float snd  = b5 ? acc[i]   : acc[i+8];
        float kept = b5 ? acc[i+8] : acc[i];
        r8[i] = kept + __shfl_xor(snd, 32);
    }
    const bool b4 = (lane & 16) != 0;
    float r4[4];
#pragma unroll
    for(int i=0;i<4;i++){
        float snd  = b4 ? r8[i]   : r8[i+4];
        float kept = b4 ? r8[i+4] : r8[i];
        r4[i] = kept + __shfl_xor(snd, 16);
    }
    const bool b3 = (lane & 8) != 0;
    float r2[2];
#pragma unroll
    for(int i=0;i<2;i++){
        float snd  = b3 ? r4[i]   : r4[i+2];
        float kept = b3 ? r4[i+2] : r4[i];
        r2[i] = kept + __shfl_xor(snd, 8);
    }
    const bool b2 = (lane & 4) != 0;
    {
        float snd  = b2 ? r2[0] : r2[1];
        float kept = b2 ? r2[1] : r2[0];
        r2[0] = kept + __shfl_xor(snd, 4);
    }
    r2[0] += __shfl_xor(r2[0], 2);
    r2[0] += __shfl_xor(r2[0], 1);

    float inv = 1.0f/sum;
    if ((lane&3)==0){
        msg2[((size_t)bh*N2+q)*16 + (lane>>2)] = r2[0]*inv;
    }

    int id[9];
#pragma unroll
    for(int i=0;i<9;i++) id[i]=i;
#pragma unroll
    for(int p=0;p<8;p++){
#pragma unroll
        for(int i=0;i<8-p;i++){
            bool sw = (ev[i+1] > ev[i]) || (ev[i+1]==ev[i] && id[i+1]<id[i]);
            float tv = sw? ev[i+1]:ev[i]; float bv2 = sw? ev[i]:ev[i+1];
            int   ti = sw? id[i+1]:id[i]; int   bi  = sw? id[i]:id[i+1];
            ev[i]=tv; ev[i+1]=bv2; id[i]=ti; id[i+1]=bi;
        }
    }
    int* ip = idx2 + ((size_t)bh*N2+q)*16;
    for(int it=0; it<16; it++){
        float bv = ev[0];
        int   bm = id[0]*64 + lane;
#pragma unroll
        for(int st=1; st<64; st<<=1){
            float ov = __shfl_xor(bv, st);
            int   om = __shfl_xor(bm, st);
            if (ov > bv || (ov==bv && om < bm)){ bv=ov; bm=om; }
        }
        if (lane==0) ip[it] = bm;
        if ((bm & 63) == lane){
#pragma unroll
            for(int i=0;i<8;i++){ ev[i]=ev[i+1]; id[i]=id[i+1]; }
            ev[8] = -1e30f;
        }
    }
}

// ---------------- level-1 refinement + rank-based top-8 (XCD-locality swizzled) ----------------
__global__ __launch_bounds__(256) void k_ref1(const float* __restrict__ q1, const float* __restrict__ k1,
    const float* __restrict__ v1, const float* __restrict__ msg2, const int* __restrict__ idx2,
    float* __restrict__ msg1, int* __restrict__ idx1)
{
    // swizzle: each XCD (blockIdx.x % 8) owns a contiguous 2-bh span -> k1/v1 working set fits its L2
    const int bid = (blockIdx.x & 7)*1152 + (blockIdx.x >> 3);
    const int gw = bid*4 + (threadIdx.x>>6);
    const int lane = threadIdx.x & 63;
    const int bh = gw / N1, n = gw - bh*N1;
    const int y = n / W1_, x = n - y*W1_;
    const int par = (y>>1)*W2_ + (x>>1);
    const int kk = lane>>2, tt = lane&3, dy = tt>>1, dx = tt&1;
    int p = idx2[((size_t)bh*N2+par)*16 + kk];
    int ky = p / W2_, kx = p - ky*W2_;
    int child = (2*ky+dy)*W1_ + 2*kx+dx;

    const float* qp = q1 + ((size_t)bh*N1+n)*16;
    float qr[16];
#pragma unroll
    for(int d=0; d<16; d+=4){
        float4 qq = *(const float4*)(qp+d);
        qr[d]=qq.x; qr[d+1]=qq.y; qr[d+2]=qq.z; qr[d+3]=qq.w;
    }
    const float4* kp = (const float4*)(k1 + ((size_t)bh*N1+child)*16);
    float s = 0.f;
#pragma unroll
    for(int dq=0;dq<4;dq++){
        float4 kv = kp[dq];
        s += qr[dq*4+0]*kv.x + qr[dq*4+1]*kv.y + qr[dq*4+2]*kv.z + qr[dq*4+3]*kv.w;
    }
    s *= TEMP;
    float e = expf(s);
    float sum = e;
#pragma unroll
    for(int st=1; st<64; st<<=1) sum += __shfl_xor(sum, st);

    float acc[16];
    const float4* vp = (const float4*)(v1 + ((size_t)bh*N1+child)*16);
#pragma unroll
    for(int dq=0;dq<4;dq++){
        float4 vv = vp[dq];
        acc[dq*4+0]=e*vv.x; acc[dq*4+1]=e*vv.y; acc[dq*4+2]=e*vv.z; acc[dq*4+3]=e*vv.w;
    }
    const bool b5 = (lane & 32) != 0;
    float r8[8];
#pragma unroll
    for(int i=0;i<8;i++){
        float snd  = b5 ? acc[i]   : acc[i+8];
        float kept = b5 ? acc[i+8] : acc[i];
        r8[i] = kept + __shfl_xor(snd, 32);
    }
    const bool b4 = (lane & 16) != 0;
    float r4[4];
#pragma unroll
    for(int i=0;i<4;i++){
        float snd  = b4 ? r8[i]   : r8[i+4];
        float kept = b4 ? r8[i+4] : r8[i];
        r4[i] = kept + __shfl_xor(snd, 16);
    }
    const bool b3 = (lane & 8) != 0;
    float r2[2];
#pragma unroll
    for(int i=0;i<2;i++){
        float snd  = b3 ? r4[i]   : r4[i+2];
        float kept = b3 ? r4[i+2] : r4[i];
        r2[i] = kept + __shfl_xor(snd, 8);
    }
    const bool b2 = (lane & 4) != 0;
    {
        float snd  = b2 ? r2[0] : r2[1];
        float kept = b2 ? r2[1] : r2[0];
        r2[0] = kept + __shfl_xor(snd, 4);
    }
    r2[0] += __shfl_xor(r2[0], 2);
    r2[0] += __shfl_xor(r2[0], 1);

    float inv = 1.0f/sum;
    if ((lane&3)==0){
        int d = lane>>2;
        msg1[((size_t)bh*N1+n)*16 + d] =
            msg2[((size_t)bh*N2+par)*16 + d] + r2[0]*inv;
    }

    int cnt = 0;
#pragma unroll
    for(int i=0;i<64;i++){
        float si = __shfl(s, i);
        if (si > s || (si == s && i < lane)) cnt++;
    }
    if (cnt < 8) idx1[((size_t)bh*N1+n)*8 + cnt] = child;
}

// ---------------- level-0 refinement, 2 queries per wave (XCD-locality swizzled) ----------------
__global__ __launch_bounds__(256) void k_ref0(const float* __restrict__ q0, const float* __restrict__ k0,
    const float* __restrict__ v0, const float* __restrict__ msg1, const int* __restrict__ idx1,
    float* __restrict__ msg0)
{
    // swizzle: each XCD owns a contiguous 2-bh span -> k0/v0 working set (2.36 MB) fits its L2
    const int bid = (blockIdx.x & 7)*2304 + (blockIdx.x >> 3);
    const int gw = bid*4 + (threadIdx.x>>6);
    const int lane = threadIdx.x & 63;
    const int sub = lane>>5, j = lane&31;
    const int qi = gw*2 + sub;
    const int bh = qi / N0, n = qi - bh*N0;
    const int y = n / W0_, x = n - y*W0_;
    const int par = (y>>1)*W1_ + (x>>1);
    const int kk = j>>2, tt = j&3, dy = tt>>1, dx = tt&1;
    int p = idx1[((size_t)bh*N1+par)*8 + kk];
    int ky = p / W1_, kx = p - ky*W1_;
    int child = (2*ky+dy)*W0_ + 2*kx+dx;

    const float* qp = q0 + ((size_t)bh*N0+n)*16;
    float qr[16];
#pragma unroll
    for(int d=0; d<16; d+=4){
        float4 qq = *(const float4*)(qp+d);
        qr[d]=qq.x; qr[d+1]=qq.y; qr[d+2]=qq.z; qr[d+3]=qq.w;
    }
    const float4* kp = (const float4*)(k0 + ((size_t)bh*N0+child)*16);
    float s = 0.f;
#pragma unroll
    for(int dq=0;dq<4;dq++){
        float4 kv = kp[dq];
        s += qr[dq*4+0]*kv.x + qr[dq*4+1]*kv.y + qr[dq*4+2]*kv.z + qr[dq*4+3]*kv.w;
    }
    s *= TEMP;
    float e = expf(s);
    float sum = e;
#pragma unroll
    for(int st=1; st<32; st<<=1) sum += __shfl_xor(sum, st);

    float acc[16];
    const float4* vp = (const float4*)(v0 + ((size_t)bh*N0+child)*16);
#pragma unroll
    for(int dq=0;dq<4;dq++){
        float4 vv = vp[dq];
        acc[dq*4+0]=e*vv.x; acc[dq*4+1]=e*vv.y; acc[dq*4+2]=e*vv.z; acc[dq*4+3]=e*vv.w;
    }
    const bool b4 = (j & 16) != 0;
    float r8[8];
#pragma unroll
    for(int i=0;i<8;i++){
        float snd  = b4 ? acc[i]   : acc[i+8];
        float kept = b4 ? acc[i+8] : acc[i];
        r8[i] = kept + __shfl_xor(snd, 16);
    }
    const bool b3 = (j & 8) != 0;
    float r4[4];
#pragma unroll
    for(int i=0;i<4;i++){
        float snd  = b3 ? r8[i]   : r8[i+4];
        float kept = b3 ? r8[i+4] : r8[i];
        r4[i] = kept + __shfl_xor(snd, 8);
    }
    const bool b2 = (j & 4) != 0;
    float r2[2];
#pragma unroll
    for(int i=0;i<2;i++){
        float snd  = b2 ? r4[i]   : r4[i+2];
        float kept = b2 ? r4[i+2] : r4[i];
        r2[i] = kept + __shfl_xor(snd, 4);
    }
    const bool b1 = (j & 2) != 0;
    {
        float snd  = b1 ? r2[0] : r2[1];
        float kept = b1 ? r2[1] : r2[0];
        r2[0] = kept + __shfl_xor(snd, 2);
    }
    r2[0] += __shfl_xor(r2[0], 1);

    float inv = 1.0f/sum;
    if ((j&1)==0){
        int d = j>>1;
        int b_ = bh>>3, h = bh&7;
        msg0[((size_t)b_*N0+n)*128 + h*16 + d] =
            msg1[((size_t)bh*N1+par)*16 + d] + r2[0]*inv;
    }
}

// ---------------- output projection GEMM + bias ----------------
__global__ __launch_bounds__(256) void k_out(const float* __restrict__ msg0, const float* __restrict__ Wo,
    const float* __restrict__ bo, float* __restrict__ out)
{
    __shared__ __align__(16) float At[16][68];
    __shared__ __align__(16) float Wt[16][132];
    const int t = threadIdx.x;
    const int m0 = blockIdx.x * 64;
    const int tx = t & 15, ty = t >> 4;

    float acc[4][8];
#pragma unroll
    for(int i=0;i<4;i++)
#pragma unroll
        for(int j=0;j<8;j++) acc[i][j]=0.f;

    const int ar = t>>2, akq = (t&3)*4;
    const int wo = t>>1, wkq = (t&1)*8;

    for(int kc=0;kc<128;kc+=16){
        float4 av = *(const float4*)(msg0 + (size_t)(m0+ar)*128 + kc + akq);
        At[akq+0][ar] = av.x;
        At[akq+1][ar] = av.y;
        At[akq+2][ar] = av.z;
        At[akq+3][ar] = av.w;
        float4 w0 = *(const float4*)(Wo + (size_t)wo*128 + kc + wkq);
        float4 w1 = *(const float4*)(Wo + (size_t)wo*128 + kc + wkq + 4);
        Wt[wkq+0][wo] = w0.x; Wt[wkq+1][wo] = w0.y;
        Wt[wkq+2][wo] = w0.z; Wt[wkq+3][wo] = w0.w;
        Wt[wkq+4][wo] = w1.x; Wt[wkq+5][wo] = w1.y;
        Wt[wkq+6][wo] = w1.z; Wt[wkq+7][wo] = w1.w;
        __syncthreads();
#pragma unroll
        for(int kk=0;kk<16;kk++){
            float4 a4 = *(const float4*)&At[kk][ty*4];
            float4 wa = *(const float4*)&Wt[kk][tx*4];
            float4 wb = *(const float4*)&Wt[kk][64 + tx*4];
            float avr[4] = {a4.x,a4.y,a4.z,a4.w};
            float wvr[8] = {wa.x,wa.y,wa.z,wa.w, wb.x,wb.y,wb.z,wb.w};
#pragma unroll
            for(int i=0;i<4;i++)
#pragma unroll
                for(int j=0;j<8;j++) acc[i][j] += avr[i]*wvr[j];
        }
        __syncthreads();
    }
#pragma unroll
    for(int i=0;i<4;i++){
        int m = m0 + ty*4 + i;
        float4 sA = make_float4(acc[i][0]+bo[tx*4+0], acc[i][1]+bo[tx*4+1],
                                acc[i][2]+bo[tx*4+2], acc[i][3]+bo[tx*4+3]);
        float4 sB = make_float4(acc[i][4]+bo[64+tx*4+0], acc[i][5]+bo[64+tx*4+1],
                                acc[i][6]+bo[64+tx*4+2], acc[i][7]+bo[64+tx*4+3]);
        *(float4*)(out + (size_t)m*128 + tx*4)      = sA;
        *(float4*)(out + (size_t)m*128 + 64 + tx*4) = sB;
    }
}

extern "C" void kernel_launch(void* const* d_in, const int* in_sizes, int n_in,
                              void* d_out, int out_size, void* d_ws, size_t ws_size,
                              hipStream_t stream) {
    const float* x  = (const float*)d_in[0];
    const float* tg = (const float*)d_in[1];
    const float* Wq = (const float*)d_in[2];
    const float* Wk = (const float*)d_in[3];
    const float* Wv = (const float*)d_in[4];
    const float* Wo = (const float*)d_in[5];
    const float* bo = (const float*)d_in[6];

    float* ws = (float*)d_ws;
    float* q0   = ws + 0;
    float* k0   = ws + 2359296;
    float* v0   = ws + 4718592;
    float* q1   = ws + 7077888;
    float* k1   = ws + 7667712;
    float* v1   = ws + 8257536;
    float* q2   = ws + 8847360;
    float* k2   = ws + 8994816;
    float* v2   = ws + 9142272;
    float* msg2 = ws + 9289728;
    float* msg1 = ws + 9437184;
    float* msg0 = ws + 10027008;
    int*   idx2 = (int*)(ws + 12386304);
    int*   idx1 = (int*)(ws + 12533760);

    k_proj<<<dim3(288,3), 256, 0, stream>>>(x, tg, Wq, Wk, Wv, q0, k0, v0);
    k_pool<96, N0, N1, 442368><<<442368/256, 256, 0, stream>>>((const float4*)q0, (float4*)q1);
    k_pool<48, N1, N2, 110592><<<110592/256, 256, 0, stream>>>((const float4*)q1, (float4*)q2);
    k_attn2<<<dim3(16,144), 256, 0, stream>>>(q2, k2, v2, msg2, idx2);
    k_ref1<<<9216, 256, 0, stream>>>(q1, k1, v1, msg2, idx2, msg1, idx1);
    k_ref0<<<18432, 256, 0, stream>>>(q0, k0, v0, msg1, idx1, msg0);
    k_out<<<288, 256, 0, stream>>>(msg0, Wo, bo, (float*)d_out);
}

// Round 9
// 272.732 us; speedup vs baseline: 1.0826x; 1.0128x over previous
//
#include <hip/hip_runtime.h>

#define NB   2
#define NHD  8
#define BH   16
#define HD   16
#define N0   9216
#define N1   2304
#define N2   576
#define W0_  96
#define W1_  48
#define W2_  24
#define M_TOT 18432
#define TEMP 0.25f

// ---------------- projection GEMM: dst[(b,h,n,d)] = sum_c A[m][c] * W[o][c] ----------------
__global__ __launch_bounds__(256) void k_proj(const float* __restrict__ x, const float* __restrict__ tg,
    const float* __restrict__ Wq, const float* __restrict__ Wk, const float* __restrict__ Wv,
    float* __restrict__ q0, float* __restrict__ k0, float* __restrict__ v0)
{
    __shared__ __align__(16) float At[16][68];   // [k][row]
    __shared__ __align__(16) float Wt[16][132];  // [k][o]
    const int t = threadIdx.x;
    const int which = blockIdx.y;
    const float* A  = (which==0)? x : tg;
    const float* Wm = (which==0)? Wq : (which==1? Wk : Wv);
    float* dst      = (which==0)? q0 : (which==1? k0 : v0);
    const int m0 = blockIdx.x * 64;
    const int tx = t & 15, ty = t >> 4;

    float acc[4][8];
#pragma unroll
    for(int i=0;i<4;i++)
#pragma unroll
        for(int j=0;j<8;j++) acc[i][j]=0.f;

    const int ar = t>>2, akq = (t&3)*4;
    const int wo = t>>1, wkq = (t&1)*8;

    for(int kc=0;kc<128;kc+=16){
        float4 av = *(const float4*)(A + (size_t)(m0+ar)*128 + kc + akq);
        At[akq+0][ar] = av.x;
        At[akq+1][ar] = av.y;
        At[akq+2][ar] = av.z;
        At[akq+3][ar] = av.w;
        float4 w0 = *(const float4*)(Wm + (size_t)wo*128 + kc + wkq);
        float4 w1 = *(const float4*)(Wm + (size_t)wo*128 + kc + wkq + 4);
        Wt[wkq+0][wo] = w0.x; Wt[wkq+1][wo] = w0.y;
        Wt[wkq+2][wo] = w0.z; Wt[wkq+3][wo] = w0.w;
        Wt[wkq+4][wo] = w1.x; Wt[wkq+5][wo] = w1.y;
        Wt[wkq+6][wo] = w1.z; Wt[wkq+7][wo] = w1.w;
        __syncthreads();
#pragma unroll
        for(int kk=0;kk<16;kk++){
            float4 a4 = *(const float4*)&At[kk][ty*4];
            float4 wa = *(const float4*)&Wt[kk][tx*4];
            float4 wb = *(const float4*)&Wt[kk][64 + tx*4];
            float avr[4] = {a4.x,a4.y,a4.z,a4.w};
            float wvr[8] = {wa.x,wa.y,wa.z,wa.w, wb.x,wb.y,wb.z,wb.w};
#pragma unroll
            for(int i=0;i<4;i++)
#pragma unroll
                for(int j=0;j<8;j++) acc[i][j] += avr[i]*wvr[j];
        }
        __syncthreads();
    }
    const int hA = tx>>2, dA = (tx&3)*4;
#pragma unroll
    for(int i=0;i<4;i++){
        int m = m0 + ty*4 + i;
        int b = m / N0; int n = m - b*N0;
        float4 sA = make_float4(acc[i][0], acc[i][1], acc[i][2], acc[i][3]);
        float4 sB = make_float4(acc[i][4], acc[i][5], acc[i][6], acc[i][7]);
        *(float4*)(dst + ((size_t)(b*NHD + hA    )*N0 + n)*16 + dA) = sA;
        *(float4*)(dst + ((size_t)(b*NHD + hA + 4)*N0 + n)*16 + dA) = sB;
    }
}

// ---------------- 2x2 average pooling level0->1, row layout ----------------
template<int Win, int Nin, int Nout, int TOTAL>
__global__ __launch_bounds__(256) void k_pool(const float4* __restrict__ src, float4* __restrict__ dst)
{
    int tid = blockIdx.x*256 + threadIdx.x;
    if (tid >= TOTAL) return;
    int d4 = tid & 3;
    int rest = tid >> 2;
    int n = rest % Nout; int g = rest / Nout;
    constexpr int Wout = Win>>1;
    int yo = n / Wout, xo = n - yo*Wout;
    int cbase = (2*yo)*Win + 2*xo;
    const float4* s = src + (size_t)g*Nin*4;
    float4 a = s[(cbase      )*4 + d4];
    float4 b = s[(cbase+1    )*4 + d4];
    float4 c = s[(cbase+Win  )*4 + d4];
    float4 d = s[(cbase+Win+1)*4 + d4];
    float4 o;
    o.x = 0.25f*(a.x+b.x+c.x+d.x);
    o.y = 0.25f*(a.y+b.y+c.y+d.y);
    o.z = 0.25f*(a.z+b.z+c.z+d.z);
    o.w = 0.25f*(a.w+b.w+c.w+d.w);
    dst[((size_t)g*Nout + n)*4 + d4] = o;
}

// ---------------- pool level1->2: q2 row layout, k2/v2 TRANSPOSED [bh][dg][m] float4 ----------------
__global__ __launch_bounds__(256) void k_pool2(const float4* __restrict__ src,
    float4* __restrict__ q2f, float4* __restrict__ k2T, float4* __restrict__ v2T)
{
    int tid = blockIdx.x*256 + threadIdx.x;
    if (tid >= 110592) return;
    int d4 = tid & 3;
    int rest = tid >> 2;
    int n = rest % N2; int g = rest / N2;       // g in [0,48): 0-15 q, 16-31 k, 32-47 v
    int yo = n / W2_, xo = n - yo*W2_;
    int cbase = (2*yo)*W1_ + 2*xo;
    const float4* s = src + (size_t)g*N1*4;
    float4 a = s[(cbase       )*4 + d4];
    float4 b = s[(cbase+1     )*4 + d4];
    float4 c = s[(cbase+W1_   )*4 + d4];
    float4 d = s[(cbase+W1_+1 )*4 + d4];
    float4 o;
    o.x = 0.25f*(a.x+b.x+c.x+d.x);
    o.y = 0.25f*(a.y+b.y+c.y+d.y);
    o.z = 0.25f*(a.z+b.z+c.z+d.z);
    o.w = 0.25f*(a.w+b.w+c.w+d.w);
    int grp = g >> 4, bh = g & 15;
    if (grp == 0)      q2f[((size_t)bh*N2 + n)*4 + d4] = o;
    else if (grp == 1) k2T[((size_t)bh*4 + d4)*N2 + n] = o;
    else               v2T[((size_t)bh*4 + d4)*N2 + n] = o;
}

// ---- level-2 full attention + top-16: LDS-free, 1 query/wave, coalesced transposed k/v ----
__global__ __launch_bounds__(256) void k_attn2(const float* __restrict__ q2, const float* __restrict__ k2,
    const float* __restrict__ v2, float* __restrict__ msg2, int* __restrict__ idx2)
{
    const int bh = blockIdx.x;
    const int wv = threadIdx.x>>6, lane = threadIdx.x&63;
    const int q = blockIdx.y*4 + wv;   // one query per wave

    float qr[16];
    const float4* qp = (const float4*)(q2 + ((size_t)bh*N2 + q)*16);
#pragma unroll
    for(int dq=0;dq<4;dq++){
        float4 va = qp[dq];
        qr[dq*4+0]=va.x; qr[dq*4+1]=va.y; qr[dq*4+2]=va.z; qr[dq*4+3]=va.w;
    }

    const float4* kT = (const float4*)k2 + (size_t)bh*4*N2;   // [dg][m]
    const float4* vT = (const float4*)v2 + (size_t)bh*4*N2;

    // pass 1: scores + running max (same fma chain order as before -> bit-identical)
    float ev[9];
    float mx = -1e30f;
#pragma unroll
    for(int t9=0;t9<9;t9++){
        int m = t9*64 + lane;
        float s = 0.f;
#pragma unroll
        for(int dg=0;dg<4;dg++){
            float4 kv = kT[dg*N2 + m];          // coalesced: lanes -> consecutive 16B
            s += qr[dg*4+0]*kv.x;
            s += qr[dg*4+1]*kv.y;
            s += qr[dg*4+2]*kv.z;
            s += qr[dg*4+3]*kv.w;
        }
        s *= TEMP;
        ev[t9]=s;
        mx = fmaxf(mx, s);
    }
#pragma unroll
    for(int st=1; st<64; st<<=1) mx = fmaxf(mx, __shfl_xor(mx, st));

    // pass 2: exp(s-mx), sum, P·V (coalesced v)
    float sum=0.f;
    float acc[16];
#pragma unroll
    for(int d=0;d<16;d++) acc[d]=0.f;
#pragma unroll
    for(int t9=0;t9<9;t9++){
        int m = t9*64 + lane;
        float e = expf(ev[t9]-mx);
        ev[t9]=e;
        sum += e;
#pragma unroll
        for(int dg=0;dg<4;dg++){
            float4 vv = vT[dg*N2 + m];
            acc[dg*4+0] += e*vv.x;
            acc[dg*4+1] += e*vv.y;
            acc[dg*4+2] += e*vv.z;
            acc[dg*4+3] += e*vv.w;
        }
    }
#pragma unroll
    for(int st=1; st<64; st<<=1) sum += __shfl_xor(sum, st);

    const bool b5 = (lane & 32) != 0;
    float r8[8];
#pragma unroll
    for(int i=0;i<8;i++){
        float snd  = b5 ? acc[i]   : acc[i+8];
        float kept = b5 ? acc[i+8] : acc[i];
        r8[i] = kept + __shfl_xor(snd, 32);
    }
    const bool b4 = (lane & 16) != 0;
    float r4[4];
#pragma unroll
    for(int i=0;i<4;i++){
        float snd  = b4 ? r8[i]   : r8[i+4];
        float kept = b4 ? r8[i+4] : r8[i];
        r4[i] = kept + __shfl_xor(snd, 16);
    }
    const bool b3 = (lane & 8) != 0;
    float r2[2];
#pragma unroll
    for(int i=0;i<2;i++){
        float snd  = b3 ? r4[i]   : r4[i+2];
        float kept = b3 ? r4[i+2] : r4[i];
        r2[i] = kept + __shfl_xor(snd, 8);
    }
    const bool b2 = (lane & 4) != 0;
    {
        float snd  = b2 ? r2[0] : r2[1];
        float kept = b2 ? r2[1] : r2[0];
        r2[0] = kept + __shfl_xor(snd, 4);
    }
    r2[0] += __shfl_xor(r2[0], 2);
    r2[0] += __shfl_xor(r2[0], 1);

    float inv = 1.0f/sum;
    if ((lane&3)==0){
        msg2[((size_t)bh*N2+q)*16 + (lane>>2)] = r2[0]*inv;
    }

    int id[9];
#pragma unroll
    for(int i=0;i<9;i++) id[i]=i;
#pragma unroll
    for(int p=0;p<8;p++){
#pragma unroll
        for(int i=0;i<8-p;i++){
            bool sw = (ev[i+1] > ev[i]) || (ev[i+1]==ev[i] && id[i+1]<id[i]);
            float tv = sw? ev[i+1]:ev[i]; float bv2 = sw? ev[i]:ev[i+1];
            int   ti = sw? id[i+1]:id[i]; int   bi  = sw? id[i]:id[i+1];
            ev[i]=tv; ev[i+1]=bv2; id[i]=ti; id[i+1]=bi;
        }
    }
    int* ip = idx2 + ((size_t)bh*N2+q)*16;
    for(int it=0; it<16; it++){
        float bv = ev[0];
        int   bm = id[0]*64 + lane;
#pragma unroll
        for(int st=1; st<64; st<<=1){
            float ov = __shfl_xor(bv, st);
            int   om = __shfl_xor(bm, st);
            if (ov > bv || (ov==bv && om < bm)){ bv=ov; bm=om; }
        }
        if (lane==0) ip[it] = bm;
        if ((bm & 63) == lane){
#pragma unroll
            for(int i=0;i<8;i++){ ev[i]=ev[i+1]; id[i]=id[i+1]; }
            ev[8] = -1e30f;
        }
    }
}

// ---------------- level-1 refinement + rank-based top-8 (XCD-locality swizzled) ----------------
__global__ __launch_bounds__(256) void k_ref1(const float* __restrict__ q1, const float* __restrict__ k1,
    const float* __restrict__ v1, const float* __restrict__ msg2, const int* __restrict__ idx2,
    float* __restrict__ msg1, int* __restrict__ idx1)
{
    const int bid = (blockIdx.x & 7)*1152 + (blockIdx.x >> 3);
    const int gw = bid*4 + (threadIdx.x>>6);
    const int lane = threadIdx.x & 63;
    const int bh = gw / N1, n = gw - bh*N1;
    const int y = n / W1_, x = n - y*W1_;
    const int par = (y>>1)*W2_ + (x>>1);
    const int kk = lane>>2, tt = lane&3, dy = tt>>1, dx = tt&1;
    int p = idx2[((size_t)bh*N2+par)*16 + kk];
    int ky = p / W2_, kx = p - ky*W2_;
    int child = (2*ky+dy)*W1_ + 2*kx+dx;

    const float* qp = q1 + ((size_t)bh*N1+n)*16;
    float qr[16];
#pragma unroll
    for(int d=0; d<16; d+=4){
        float4 qq = *(const float4*)(qp+d);
        qr[d]=qq.x; qr[d+1]=qq.y; qr[d+2]=qq.z; qr[d+3]=qq.w;
    }
    const float4* kp = (const float4*)(k1 + ((size_t)bh*N1+child)*16);
    float s = 0.f;
#pragma unroll
    for(int dq=0;dq<4;dq++){
        float4 kv = kp[dq];
        s += qr[dq*4+0]*kv.x + qr[dq*4+1]*kv.y + qr[dq*4+2]*kv.z + qr[dq*4+3]*kv.w;
    }
    s *= TEMP;
    float e = expf(s);
    float sum = e;
#pragma unroll
    for(int st=1; st<64; st<<=1) sum += __shfl_xor(sum, st);

    float acc[16];
    const float4* vp = (const float4*)(v1 + ((size_t)bh*N1+child)*16);
#pragma unroll
    for(int dq=0;dq<4;dq++){
        float4 vv = vp[dq];
        acc[dq*4+0]=e*vv.x; acc[dq*4+1]=e*vv.y; acc[dq*4+2]=e*vv.z; acc[dq*4+3]=e*vv.w;
    }
    const bool b5 = (lane & 32) != 0;
    float r8[8];
#pragma unroll
    for(int i=0;i<8;i++){
        float snd  = b5 ? acc[i]   : acc[i+8];
        float kept = b5 ? acc[i+8] : acc[i];
        r8[i] = kept + __shfl_xor(snd, 32);
    }
    const bool b4 = (lane & 16) != 0;
    float r4[4];
#pragma unroll
    for(int i=0;i<4;i++){
        float snd  = b4 ? r8[i]   : r8[i+4];
        float kept = b4 ? r8[i+4] : r8[i];
        r4[i] = kept + __shfl_xor(snd, 16);
    }
    const bool b3 = (lane & 8) != 0;
    float r2[2];
#pragma unroll
    for(int i=0;i<2;i++){
        float snd  = b3 ? r4[i]   : r4[i+2];
        float kept = b3 ? r4[i+2] : r4[i];
        r2[i] = kept + __shfl_xor(snd, 8);
    }
    const bool b2 = (lane & 4) != 0;
    {
        float snd  = b2 ? r2[0] : r2[1];
        float kept = b2 ? r2[1] : r2[0];
        r2[0] = kept + __shfl_xor(snd, 4);
    }
    r2[0] += __shfl_xor(r2[0], 2);
    r2[0] += __shfl_xor(r2[0], 1);

    float inv = 1.0f/sum;
    if ((lane&3)==0){
        int d = lane>>2;
        msg1[((size_t)bh*N1+n)*16 + d] =
            msg2[((size_t)bh*N2+par)*16 + d] + r2[0]*inv;
    }

    int cnt = 0;
#pragma unroll
    for(int i=0;i<64;i++){
        float si = __shfl(s, i);
        if (si > s || (si == s && i < lane)) cnt++;
    }
    if (cnt < 8) idx1[((size_t)bh*N1+n)*8 + cnt] = child;
}

// ---------------- level-0 refinement, 2 queries per wave (XCD-locality swizzled) ----------------
__global__ __launch_bounds__(256) void k_ref0(const float* __restrict__ q0, const float* __restrict__ k0,
    const float* __restrict__ v0, const float* __restrict__ msg1, const int* __restrict__ idx1,
    float* __restrict__ msg0)
{
    const int bid = (blockIdx.x & 7)*2304 + (blockIdx.x >> 3);
    const int gw = bid*4 + (threadIdx.x>>6);
    const int lane = threadIdx.x & 63;
    const int sub = lane>>5, j = lane&31;
    const int qi = gw*2 + sub;
    const int bh = qi / N0, n = qi - bh*N0;
    const int y = n / W0_, x = n - y*W0_;
    const int par = (y>>1)*W1_ + (x>>1);
    const int kk = j>>2, tt = j&3, dy = tt>>1, dx = tt&1;
    int p = idx1[((size_t)bh*N1+par)*8 + kk];
    int ky = p / W1_, kx = p - ky*W1_;
    int child = (2*ky+dy)*W0_ + 2*kx+dx;

    const float* qp = q0 + ((size_t)bh*N0+n)*16;
    float qr[16];
#pragma unroll
    for(int d=0; d<16; d+=4){
        float4 qq = *(const float4*)(qp+d);
        qr[d]=qq.x; qr[d+1]=qq.y; qr[d+2]=qq.z; qr[d+3]=qq.w;
    }
    const float4* kp = (const float4*)(k0 + ((size_t)bh*N0+child)*16);
    float s = 0.f;
#pragma unroll
    for(int dq=0;dq<4;dq++){
        float4 kv = kp[dq];
        s += qr[dq*4+0]*kv.x + qr[dq*4+1]*kv.y + qr[dq*4+2]*kv.z + qr[dq*4+3]*kv.w;
    }
    s *= TEMP;
    float e = expf(s);
    float sum = e;
#pragma unroll
    for(int st=1; st<32; st<<=1) sum += __shfl_xor(sum, st);

    float acc[16];
    const float4* vp = (const float4*)(v0 + ((size_t)bh*N0+child)*16);
#pragma unroll
    for(int dq=0;dq<4;dq++){
        float4 vv = vp[dq];
        acc[dq*4+0]=e*vv.x; acc[dq*4+1]=e*vv.y; acc[dq*4+2]=e*vv.z; acc[dq*4+3]=e*vv.w;
    }
    const bool b4 = (j & 16) != 0;
    float r8[8];
#pragma unroll
    for(int i=0;i<8;i++){
        float snd  = b4 ? acc[i]   : acc[i+8];
        float kept = b4 ? acc[i+8] : acc[i];
        r8[i] = kept + __shfl_xor(snd, 16);
    }
    const bool b3 = (j & 8) != 0;
    float r4[4];
#pragma unroll
    for(int i=0;i<4;i++){
        float snd  = b3 ? r8[i]   : r8[i+4];
        float kept = b3 ? r8[i+4] : r8[i];
        r4[i] = kept + __shfl_xor(snd, 8);
    }
    const bool b2 = (j & 4) != 0;
    float r2[2];
#pragma unroll
    for(int i=0;i<2;i++){
        float snd  = b2 ? r4[i]   : r4[i+2];
        float kept = b2 ? r4[i+2] : r4[i];
        r2[i] = kept + __shfl_xor(snd, 4);
    }
    const bool b1 = (j & 2) != 0;
    {
        float snd  = b1 ? r2[0] : r2[1];
        float kept = b1 ? r2[1] : r2[0];
        r2[0] = kept + __shfl_xor(snd, 2);
    }
    r2[0] += __shfl_xor(r2[0], 1);

    float inv = 1.0f/sum;
    if ((j&1)==0){
        int d = j>>1;
        int b_ = bh>>3, h = bh&7;
        msg0[((size_t)b_*N0+n)*128 + h*16 + d] =
            msg1[((size_t)bh*N1+par)*16 + d] + r2[0]*inv;
    }
}

// ---------------- output projection GEMM + bias ----------------
__global__ __launch_bounds__(256) void k_out(const float* __restrict__ msg0, const float* __restrict__ Wo,
    const float* __restrict__ bo, float* __restrict__ out)
{
    __shared__ __align__(16) float At[16][68];
    __shared__ __align__(16) float Wt[16][132];
    const int t = threadIdx.x;
    const int m0 = blockIdx.x * 64;
    const int tx = t & 15, ty = t >> 4;

    float acc[4][8];
#pragma unroll
    for(int i=0;i<4;i++)
#pragma unroll
        for(int j=0;j<8;j++) acc[i][j]=0.f;

    const int ar = t>>2, akq = (t&3)*4;
    const int wo = t>>1, wkq = (t&1)*8;

    for(int kc=0;kc<128;kc+=16){
        float4 av = *(const float4*)(msg0 + (size_t)(m0+ar)*128 + kc + akq);
        At[akq+0][ar] = av.x;
        At[akq+1][ar] = av.y;
        At[akq+2][ar] = av.z;
        At[akq+3][ar] = av.w;
        float4 w0 = *(const float4*)(Wo + (size_t)wo*128 + kc + wkq);
        float4 w1 = *(const float4*)(Wo + (size_t)wo*128 + kc + wkq + 4);
        Wt[wkq+0][wo] = w0.x; Wt[wkq+1][wo] = w0.y;
        Wt[wkq+2][wo] = w0.z; Wt[wkq+3][wo] = w0.w;
        Wt[wkq+4][wo] = w1.x; Wt[wkq+5][wo] = w1.y;
        Wt[wkq+6][wo] = w1.z; Wt[wkq+7][wo] = w1.w;
        __syncthreads();
#pragma unroll
        for(int kk=0;kk<16;kk++){
            float4 a4 = *(const float4*)&At[kk][ty*4];
            float4 wa = *(const float4*)&Wt[kk][tx*4];
            float4 wb = *(const float4*)&Wt[kk][64 + tx*4];
            float avr[4] = {a4.x,a4.y,a4.z,a4.w};
            float wvr[8] = {wa.x,wa.y,wa.z,wa.w, wb.x,wb.y,wb.z,wb.w};
#pragma unroll
            for(int i=0;i<4;i++)
#pragma unroll
                for(int j=0;j<8;j++) acc[i][j] += avr[i]*wvr[j];
        }
        __syncthreads();
    }
#pragma unroll
    for(int i=0;i<4;i++){
        int m = m0 + ty*4 + i;
        float4 sA = make_float4(acc[i][0]+bo[tx*4+0], acc[i][1]+bo[tx*4+1],
                                acc[i][2]+bo[tx*4+2], acc[i][3]+bo[tx*4+3]);
        float4 sB = make_float4(acc[i][4]+bo[64+tx*4+0], acc[i][5]+bo[64+tx*4+1],
                                acc[i][6]+bo[64+tx*4+2], acc[i][7]+bo[64+tx*4+3]);
        *(float4*)(out + (size_t)m*128 + tx*4)      = sA;
        *(float4*)(out + (size_t)m*128 + 64 + tx*4) = sB;
    }
}

extern "C" void kernel_launch(void* const* d_in, const int* in_sizes, int n_in,
                              void* d_out, int out_size, void* d_ws, size_t ws_size,
                              hipStream_t stream) {
    const float* x  = (const float*)d_in[0];
    const float* tg = (const float*)d_in[1];
    const float* Wq = (const float*)d_in[2];
    const float* Wk = (const float*)d_in[3];
    const float* Wv = (const float*)d_in[4];
    const float* Wo = (const float*)d_in[5];
    const float* bo = (const float*)d_in[6];

    float* ws = (float*)d_ws;
    float* q0   = ws + 0;
    float* k0   = ws + 2359296;
    float* v0   = ws + 4718592;
    float* q1   = ws + 7077888;
    float* k1   = ws + 7667712;
    float* v1   = ws + 8257536;
    float* q2   = ws + 8847360;
    float* k2   = ws + 8994816;   // now holds k2T [bh][dg][m] float4
    float* v2   = ws + 9142272;   // now holds v2T
    float* msg2 = ws + 9289728;
    float* msg1 = ws + 9437184;
    float* msg0 = ws + 10027008;
    int*   idx2 = (int*)(ws + 12386304);
    int*   idx1 = (int*)(ws + 12533760);

    k_proj<<<dim3(288,3), 256, 0, stream>>>(x, tg, Wq, Wk, Wv, q0, k0, v0);
    k_pool<96, N0, N1, 442368><<<442368/256, 256, 0, stream>>>((const float4*)q0, (float4*)q1);
    k_pool2<<<432, 256, 0, stream>>>((const float4*)q1, (float4*)q2, (float4*)k2, (float4*)v2);
    k_attn2<<<dim3(16,144), 256, 0, stream>>>(q2, k2, v2, msg2, idx2);
    k_ref1<<<9216, 256, 0, stream>>>(q1, k1, v1, msg2, idx2, msg1, idx1);
    k_ref0<<<18432, 256, 0, stream>>>(q0, k0, v0, msg1, idx1, msg0);
    k_out<<<288, 256, 0, stream>>>(msg0, Wo, bo, (float*)d_out);
}